// Round 8
// baseline (579.473 us; speedup 1.0000x reference)
//
#include <hip/hip_runtime.h>
#include <math.h>

// Problem constants
#define NB   256   // batch
#define NIN  1024  // in_features
#define NOUT 1024  // out_features
#define NSF  128   // sub_features (rank)
#define NQ   1024  // q_features
#define NS   64    // num subnets
#define NACT 8     // top-k active
#define NSLOT 64   // per-subnet slot capacity (nb ~ Binom: mean 32, max ~50)
#define NIC  8     // i-chunks in B1 (chunk = 128)

// Workspace layout (bytes). Total ~25.3 MB.
#define WS_COUNTS 0          // 64 ints   (zeroed with att in one memset)
#define WS_ATT    1024       // float[256][64] attention accumulators (zeroed)
#define WS_LISTBK 66560      // int  [64][64]
#define WS_LISTW  82944      // float[64][64]
#define WS_Y      99328      // float[2048][1024] Ybuf[b*8+k][o]            (8.39 MB)
#define WS_H      8487936    // float[8][64][128][64] Hpart[ic][s][r][slot] (16.78 MB)

// ---------------------------------------------------------------------------
// Kernel A1: att[b][s] += q[b, kc*256:+256] . Wk[s, same]  (split-K x4,
// atomicAdd into zeroed att; bias added in topk). grid (32,8,4) = 1024 blocks.
// ---------------------------------------------------------------------------
__global__ __launch_bounds__(256) void attn_gemm(
    const float* __restrict__ q, const float* __restrict__ Wk,
    float* __restrict__ att)
{
    int bt = blockIdx.x;        // 8 batch rows
    int st = blockIdx.y;        // 8 subnets
    int kc = blockIdx.z;        // k-chunk of 256
    int t  = threadIdx.x;
    int r  = t >> 5;            // 0..7
    int c  = (t >> 2) & 7;      // 0..7
    int il = t & 3;

    const float4* qp = (const float4*)(q  + (size_t)(bt * 8 + r) * NQ + kc * 256) + il;
    const float4* wp = (const float4*)(Wk + (size_t)(st * 8 + c) * NQ + kc * 256) + il;
    float acc = 0.f;
    #pragma unroll
    for (int k = 0; k < 16; ++k) {
        float4 a = qp[k * 4];
        float4 w = wp[k * 4];
        acc += a.x * w.x + a.y * w.y + a.z * w.z + a.w * w.w;
    }
    acc += __shfl_xor(acc, 1);
    acc += __shfl_xor(acc, 2);
    if (il == 0)
        atomicAdd(&att[(size_t)(bt * 8 + r) * NS + st * 8 + c], acc);
}

// ---------------------------------------------------------------------------
// Kernel A2: per-row top-8 + softmax + append. 256 blocks x 64 threads.
// ---------------------------------------------------------------------------
__global__ __launch_bounds__(64) void topk_k(
    const float* __restrict__ att, const float* __restrict__ bk,
    int* __restrict__ counts, int* __restrict__ list_bk,
    float* __restrict__ list_w)
{
    int b = blockIdx.x;
    int t = threadIdx.x;   // 0..63 = subnet
    float v = att[(size_t)b * NS + t] + bk[t];
    float top_v[NACT]; int top_i[NACT];
    #pragma unroll
    for (int k = 0; k < NACT; ++k) {
        float mv = v; int mi = t;
        #pragma unroll
        for (int off = 1; off < 64; off <<= 1) {
            float ov = __shfl_xor(mv, off);
            int   oi = __shfl_xor(mi, off);
            if (ov > mv || (ov == mv && oi < mi)) { mv = ov; mi = oi; }
        }
        top_v[k] = mv; top_i[k] = mi;
        if (t == mi) v = -INFINITY;
    }
    if (t == 0) {
        float m = top_v[0], den = 0.f, e[NACT];
        #pragma unroll
        for (int k = 0; k < NACT; ++k) { e[k] = expf(top_v[k] - m); den += e[k]; }
        float inv = 1.f / den;
        #pragma unroll
        for (int k = 0; k < NACT; ++k) {
            int s = top_i[k];
            int slot = atomicAdd(&counts[s], 1);
            if (slot < NSLOT) {
                list_bk[s * NSLOT + slot] = b * NACT + k;
                list_w[s * NSLOT + slot]  = e[k] * inv;
            }
        }
    }
}

// ---------------------------------------------------------------------------
// Kernel B1: Hpart[ic][s][r][j] = V0[s, r, ic*128:+128] . x[b_j, same]
// grid (64 s, 2rt x 8ic, 2 jt) = 2048 blocks (~1480 meaty, ~5.8/CU).
// Tile 64r x 32j x 128i; thread = 2r x 4j. x staged in LDS; V0 streams
// global->reg->FMA barrier-free with one-group register lookahead.
// ---------------------------------------------------------------------------
__global__ __launch_bounds__(256) void subnet_h(
    const float* __restrict__ x, const float* __restrict__ V0,
    const int* __restrict__ counts, const int* __restrict__ list_bk,
    float* __restrict__ Hpart)
{
    int s  = blockIdx.x;
    int rt = blockIdx.y & 1;       // r-tile of 64
    int ic = blockIdx.y >> 1;      // i-chunk of 128
    int jt = blockIdx.z;
    int nb = counts[s]; if (nb > NSLOT) nb = NSLOT;
    if (jt * 32 >= nb) return;
    int t = threadIdx.x;

    __shared__ float xs[128][36];   // [i][j], pad 36 (16B-aligned rows)
    __shared__ int   bidx[32];

    if (t < 32) {
        int idx = jt * 32 + t;
        bidx[t] = (idx < nb) ? (list_bk[s * NSLOT + idx] >> 3) : 0;
    }
    __syncthreads();

    // stage x chunk: 32 j x 128 i
    int lj = t >> 3;                // j 0..31
    int lc = t & 7;                 // 0..7
    {
        const float4* xrow = (const float4*)(x + (size_t)bidx[lj] * NIN + ic * 128);
        float4 xf[4];
        #pragma unroll
        for (int k = 0; k < 4; ++k) xf[k] = xrow[lc + 8 * k];
        #pragma unroll
        for (int k = 0; k < 4; ++k) {
            int i = (lc + 8 * k) * 4;
            xs[i + 0][lj] = xf[k].x; xs[i + 1][lj] = xf[k].y;
            xs[i + 2][lj] = xf[k].z; xs[i + 3][lj] = xf[k].w;
        }
    }

    int tr = t >> 3;                // r-pair 0..31
    int tj = t & 7;                 // j-quad 0..7
    int r0 = rt * 64 + tr * 2;
    const float4* v0a = (const float4*)(V0 + ((size_t)s * NSF + r0) * NIN + ic * 128);
    const float4* v0b = v0a + (NIN / 4);

    float acc[2][4] = {};
    float4 pa[4], pb[4];
    #pragma unroll
    for (int k = 0; k < 4; ++k) { pa[k] = v0a[k]; pb[k] = v0b[k]; }
    __syncthreads();

    #pragma unroll
    for (int g = 0; g < 8; ++g) {
        float4 ca[4], cb[4];
        #pragma unroll
        for (int k = 0; k < 4; ++k) { ca[k] = pa[k]; cb[k] = pb[k]; }
        if (g < 7) {   // issue next group's loads before FMAs on this group
            #pragma unroll
            for (int k = 0; k < 4; ++k) {
                pa[k] = v0a[(g + 1) * 4 + k];
                pb[k] = v0b[(g + 1) * 4 + k];
            }
        }
        #pragma unroll
        for (int k = 0; k < 4; ++k) {
            int i4 = g * 4 + k;
            const float* xc = &xs[i4 * 4][tj << 2];
            float4 h0 = *(const float4*)(xc);
            float4 h1 = *(const float4*)(xc + 36);
            float4 h2 = *(const float4*)(xc + 72);
            float4 h3 = *(const float4*)(xc + 108);
            float4 a = ca[k], b = cb[k];
            acc[0][0] += a.x * h0.x; acc[0][1] += a.x * h0.y; acc[0][2] += a.x * h0.z; acc[0][3] += a.x * h0.w;
            acc[1][0] += b.x * h0.x; acc[1][1] += b.x * h0.y; acc[1][2] += b.x * h0.z; acc[1][3] += b.x * h0.w;
            acc[0][0] += a.y * h1.x; acc[0][1] += a.y * h1.y; acc[0][2] += a.y * h1.z; acc[0][3] += a.y * h1.w;
            acc[1][0] += b.y * h1.x; acc[1][1] += b.y * h1.y; acc[1][2] += b.y * h1.z; acc[1][3] += b.y * h1.w;
            acc[0][0] += a.z * h2.x; acc[0][1] += a.z * h2.y; acc[0][2] += a.z * h2.z; acc[0][3] += a.z * h2.w;
            acc[1][0] += b.z * h2.x; acc[1][1] += b.z * h2.y; acc[1][2] += b.z * h2.z; acc[1][3] += b.z * h2.w;
            acc[0][0] += a.w * h3.x; acc[0][1] += a.w * h3.y; acc[0][2] += a.w * h3.z; acc[0][3] += a.w * h3.w;
            acc[1][0] += b.w * h3.x; acc[1][1] += b.w * h3.y; acc[1][2] += b.w * h3.z; acc[1][3] += b.w * h3.w;
        }
    }

    // Hpart[ic][s][r][j]: contiguous float4 stores (8-lane 128B runs)
    float* Hp = Hpart + (((size_t)ic * NS + s) * NSF + r0) * NSLOT + jt * 32 + (tj << 2);
    *(float4*)Hp           = make_float4(acc[0][0], acc[0][1], acc[0][2], acc[0][3]);
    *(float4*)(Hp + NSLOT) = make_float4(acc[1][0], acc[1][1], acc[1][2], acc[1][3]);
}

// ---------------------------------------------------------------------------
// Kernel B2: Y[o,j] = V1[s,o,:] . (sum_ic Hpart)[s,:,j];
// Ybuf[bk_j][o] = w_j * Y. grid (64 s, 16 ot, 2 jt). Tile 64o x 32j;
// thread = 2o x 4j. H staged once (fold 8 partials, coalesced reads), then
// barrier-free K-loop streaming V1 with one-group lookahead.
// ---------------------------------------------------------------------------
__global__ __launch_bounds__(256) void subnet_out(
    const float* __restrict__ V1, const int* __restrict__ counts,
    const int* __restrict__ list_bk, const float* __restrict__ list_w,
    const float* __restrict__ Hpart, float* __restrict__ Ybuf)
{
    int s  = blockIdx.x;
    int ot = blockIdx.y;           // o-tile of 64
    int jt = blockIdx.z;
    int nb = counts[s]; if (nb > NSLOT) nb = NSLOT;
    if (jt * 32 >= nb) return;
    int t = threadIdx.x;

    __shared__ float hs[128][36];  // [r][j]
    __shared__ int   bkx[32];
    __shared__ float wjs[32];

    if (t < 32) {
        int idx = jt * 32 + t;
        bool v = idx < nb;
        bkx[t] = v ? list_bk[s * NSLOT + idx] : 0;
        wjs[t] = v ? list_w[s * NSLOT + idx] : 0.f;
    }

    // stage hs[r][j] = sum of 8 i-chunk partials ([ic][s][r][j] layout:
    // contiguous j reads, float4-coalesced)
    {
        int r  = t >> 1;             // 0..127
        int jq = (t & 1) * 4;        // float4 index base 0 or 4
        const float* Hp = Hpart + ((size_t)s * NSF + r) * NSLOT + jt * 32;
        const size_t HS = (size_t)NS * NSF * NSLOT;
        #pragma unroll
        for (int rep = 0; rep < 4; ++rep) {
            const float* hp = Hp + (jq + rep) * 4;
            float4 u = *(const float4*)(hp);
            #pragma unroll
            for (int icp = 1; icp < NIC; ++icp) {
                float4 v = *(const float4*)(hp + icp * HS);
                u.x += v.x; u.y += v.y; u.z += v.z; u.w += v.w;
            }
            *(float4*)&hs[r][(jq + rep) * 4] = u;
        }
    }
    __syncthreads();

    int to = t >> 3;               // o-pair 0..31
    int tj = t & 7;                // j-quad
    int o0 = ot * 64 + to * 2;
    const float4* r0p = (const float4*)(V1 + ((size_t)s * NOUT + o0) * NSF);
    const float4* r1p = r0p + (NSF / 4);
    float acc[2][4] = {};

    float4 pa[4], pb[4];
    #pragma unroll
    for (int k = 0; k < 4; ++k) { pa[k] = r0p[k]; pb[k] = r1p[k]; }

    #pragma unroll
    for (int g = 0; g < 8; ++g) {
        float4 ca[4], cb[4];
        #pragma unroll
        for (int k = 0; k < 4; ++k) { ca[k] = pa[k]; cb[k] = pb[k]; }
        if (g < 7) {
            #pragma unroll
            for (int k = 0; k < 4; ++k) {
                pa[k] = r0p[(g + 1) * 4 + k];
                pb[k] = r1p[(g + 1) * 4 + k];
            }
        }
        #pragma unroll
        for (int k = 0; k < 4; ++k) {
            int r4 = g * 4 + k;
            const float* hc = &hs[r4 * 4][tj << 2];
            float4 h0 = *(const float4*)(hc);
            float4 h1 = *(const float4*)(hc + 36);
            float4 h2 = *(const float4*)(hc + 72);
            float4 h3 = *(const float4*)(hc + 108);
            float4 a = ca[k], b = cb[k];
            acc[0][0] += a.x * h0.x; acc[0][1] += a.x * h0.y; acc[0][2] += a.x * h0.z; acc[0][3] += a.x * h0.w;
            acc[1][0] += b.x * h0.x; acc[1][1] += b.x * h0.y; acc[1][2] += b.x * h0.z; acc[1][3] += b.x * h0.w;
            acc[0][0] += a.y * h1.x; acc[0][1] += a.y * h1.y; acc[0][2] += a.y * h1.z; acc[0][3] += a.y * h1.w;
            acc[1][0] += b.y * h1.x; acc[1][1] += b.y * h1.y; acc[1][2] += b.y * h1.z; acc[1][3] += b.y * h1.w;
            acc[0][0] += a.z * h2.x; acc[0][1] += a.z * h2.y; acc[0][2] += a.z * h2.z; acc[0][3] += a.z * h2.w;
            acc[1][0] += b.z * h2.x; acc[1][1] += b.z * h2.y; acc[1][2] += b.z * h2.z; acc[1][3] += b.z * h2.w;
            acc[0][0] += a.w * h3.x; acc[0][1] += a.w * h3.y; acc[0][2] += a.w * h3.z; acc[0][3] += a.w * h3.w;
            acc[1][0] += b.w * h3.x; acc[1][1] += b.w * h3.y; acc[1][2] += b.w * h3.z; acc[1][3] += b.w * h3.w;
        }
    }

    #pragma unroll
    for (int ji = 0; ji < 4; ++ji) {
        int sl  = (tj << 2) + ji;
        int idx = jt * 32 + sl;
        if (idx < nb) {
            float w = wjs[sl];
            *(float2*)(Ybuf + (size_t)bkx[sl] * NOUT + o0) =
                make_float2(w * acc[0][ji], w * acc[1][ji]);
        }
    }
}

// ---------------------------------------------------------------------------
// Kernel C: out[b][o] = sum_k Ybuf[b*8+k][o]. 256 blocks x 256 thr, float4.
// ---------------------------------------------------------------------------
__global__ __launch_bounds__(256) void reduce_out(
    const float* __restrict__ Ybuf, float* __restrict__ out)
{
    int gid = blockIdx.x * 256 + threadIdx.x;
    const float4* yb = (const float4*)Ybuf + (size_t)(gid >> 8) * (NACT * 256) + (gid & 255);
    float4 r = yb[0];
    #pragma unroll
    for (int k = 1; k < NACT; ++k) {
        float4 u = yb[(size_t)k * 256];
        r.x += u.x; r.y += u.y; r.z += u.z; r.w += u.w;
    }
    ((float4*)out)[gid] = r;
}

// ---------------------------------------------------------------------------
extern "C" void kernel_launch(void* const* d_in, const int* in_sizes, int n_in,
                              void* d_out, int out_size, void* d_ws, size_t ws_size,
                              hipStream_t stream)
{
    const float* x  = (const float*)d_in[0];
    const float* q  = (const float*)d_in[1];
    const float* Wk = (const float*)d_in[2];
    const float* bk = (const float*)d_in[3];
    const float* V0 = (const float*)d_in[4];
    const float* V1 = (const float*)d_in[5];
    float* out = (float*)d_out;

    char* ws = (char*)d_ws;
    int*   counts  = (int*)(ws + WS_COUNTS);
    float* att     = (float*)(ws + WS_ATT);
    int*   list_bk = (int*)(ws + WS_LISTBK);
    float* list_w  = (float*)(ws + WS_LISTW);
    float* Ybuf    = (float*)(ws + WS_Y);
    float* Hpart   = (float*)(ws + WS_H);

    // zero counts + att accumulators in one memset
    hipMemsetAsync(ws, 0, WS_ATT + NB * NS * sizeof(float), stream);

    attn_gemm<<<dim3(32, 8, 4), 256, 0, stream>>>(q, Wk, att);
    topk_k<<<dim3(NB), 64, 0, stream>>>(att, bk, counts, list_bk, list_w);
    subnet_h<<<dim3(NS, 16, 2), 256, 0, stream>>>(x, V0, counts, list_bk, Hpart);
    subnet_out<<<dim3(NS, 16, 2), 256, 0, stream>>>(V1, counts, list_bk, list_w, Hpart, Ybuf);
    reduce_out<<<dim3(NB), 256, 0, stream>>>(Ybuf, out);
}